// Round 8
// baseline (100.262 us; speedup 1.0000x reference)
//
#include <hip/hip_runtime.h>

// FOFE windowed encoder — sweep-ordered, flat linear writer.
// out[b,c,i,t] = z[t-1] - alpha^{w_i} * z[t-1-w_i];  z[t]=alpha*z[t-1]+x[t]
// w_i = i (i<48), w_48 = 64. out shape (8,512,49,513) f32 (~412 MB).
//
// R6 (sweep-ordered, row-per-wave) = 85.9 us; imbalance (wave0: 7 rows vs 6)
// + 8 scattered 2KB row-streams per block left ~30% on the table vs fill.
// Here phase 2 is a FLAT sweep: 512 threads walk the slab's f32x4s in linear
// address order (i = e/513 via magic mul), equal work per wave, one
// contiguous ~32KB write front per block. Scans + alpha^w LUTs staged once.

#define CC 512
#define LL 512
#define NW 49
#define LO 513
#define SLAB (NW * LO)        // 25137 floats per (b,c)
#define GRID 256
#define NTAU 16               // 4096 slabs / 256 blocks
#define ZOFF 65               // z[q] at k = ZOFF + q; zeros for k < 65
#define ZROW 640

typedef float f32x4 __attribute__((ext_vector_type(4)));

// XOR-swizzle for stride-4 lane access: inject idx bits [6:5] into bank bits
// [1:0] -> 2 lanes/bank (free, m136). Involution, bijective on [0,640).
__device__ __forceinline__ int swz(int i) { return i ^ ((i >> 5) & 3); }

__global__ __launch_bounds__(512)
void fofe_kernel(const float* __restrict__ x,
                 const float* __restrict__ alpha,
                 float* __restrict__ out)
{
    __shared__ float zs[NTAU][ZROW];    // 40 KB
    __shared__ float lut[NTAU][NW];     // alpha^{w_i} per slab, 3.1 KB

    const int tid  = threadIdx.x;
    const int wid  = tid >> 6;          // 0..7
    const int lane = tid & 63;
    const int blk  = blockIdx.x;

    // ---------- phase 1: all 16 row-scans (wave w: tau = w, w+8) ----------
    for (int tau = wid; tau < NTAU; tau += 8) {
        const int g = tau * GRID + blk;
        const float al = alpha[g & (CC - 1)];
        const float* xr = x + (size_t)g * LL;

        const f32x4 xv0 = reinterpret_cast<const f32x4*>(xr)[lane * 2];
        const f32x4 xv1 = reinterpret_cast<const f32x4*>(xr)[lane * 2 + 1];
        const float xe[8] = {xv0.x, xv0.y, xv0.z, xv0.w,
                             xv1.x, xv1.y, xv1.z, xv1.w};
        float l[8];
        {
            float s = 0.f;
            #pragma unroll
            for (int m = 0; m < 8; ++m) { s = fmaf(al, s, xe[m]); l[m] = s; }
        }
        float pw[8];                    // alpha^{m+1}
        {
            float p = al;
            #pragma unroll
            for (int m = 0; m < 8; ++m) { pw[m] = p; p *= al; }
        }
        float A = pw[7], S = l[7];
        #pragma unroll
        for (int off = 1; off < 64; off <<= 1) {
            const float Ap = __shfl_up(A, off);
            const float Sp = __shfl_up(S, off);
            if (lane >= off) { S = fmaf(A, Sp, S); A = A * Ap; }
        }
        float carry = __shfl_up(S, 1);
        if (lane == 0) carry = 0.f;

        float* z = zs[tau];
        z[swz(lane)] = 0.f;             // k = 0..63
        if (lane == 0) z[swz(64)] = 0.f;// k = 64 (z[-1])
        #pragma unroll
        for (int m = 0; m < 8; ++m)
            z[swz(ZOFF + lane * 8 + m)] = fmaf(pw[m], carry, l[m]);
    }
    // alpha^w LUTs (49 threads x 16 taus; cheap one-time)
    if (tid < NW) {
        const int w = (tid < 48) ? tid : 64;
        for (int tau = 0; tau < NTAU; ++tau) {
            const int g = tau * GRID + blk;
            const float al = alpha[g & (CC - 1)];
            float p = 1.f, m = al;
            #pragma unroll
            for (int b = 0; b < 7; ++b) { if (w & (1 << b)) p *= m; m *= m; }
            lut[tau][tid] = p;
        }
    }
    __syncthreads();

    // ---------- phase 2: flat linear sweep, slabs tau = 0..15 ----------
    for (int tau = 0; tau < NTAU; ++tau) {
        const int g = tau * GRID + blk;
        const float* z  = zs[tau];
        const float* lu = lut[tau];
        float* oslab = out + (size_t)g * SLAB;

        auto eval1 = [&](int e) -> float {
            const unsigned i = (unsigned)e / 513u;
            const int t = e - (int)i * 513;
            const int w = (i < 48u) ? (int)i : 64;
            return fmaf(-lu[i], z[swz(ZOFF - 1 + t - w)], z[swz(ZOFF - 1 + t)]);
        };

        // slab start phase = (g*25137) & 3 = g & 3
        const int peel  = (4 - (g & 3)) & 3;
        const int nf4   = (SLAB - peel) >> 2;
        const int ntail = (SLAB - peel) & 3;

        if (tid < peel)  oslab[tid] = eval1(tid);
        if (tid < ntail) oslab[peel + 4 * nf4 + tid] = eval1(peel + 4 * nf4 + tid);

        for (int f = tid; f < nf4; f += 512) {
            const int e = peel + 4 * f;
            const unsigned i = (unsigned)e / 513u;   // magic-mul divide
            const int t = e - (int)i * 513;

            if (t <= 509) {                 // all 4 elems in row i
                const int   w   = (i < 48u) ? (int)i : 64;
                const float apw = lu[i];
                const int   k0  = ZOFF - 1 + t;
                f32x4 v;
                v.x = fmaf(-apw, z[swz(k0     - w)], z[swz(k0    )]);
                v.y = fmaf(-apw, z[swz(k0 + 1 - w)], z[swz(k0 + 1)]);
                v.z = fmaf(-apw, z[swz(k0 + 2 - w)], z[swz(k0 + 2)]);
                v.w = fmaf(-apw, z[swz(k0 + 3 - w)], z[swz(k0 + 3)]);
                *reinterpret_cast<f32x4*>(oslab + e) = v;   // 16B-aligned
            } else {                        // row boundary straddle (<1%)
                f32x4 v;
                v.x = eval1(e);
                v.y = eval1(e + 1);
                v.z = eval1(e + 2);
                v.w = eval1(e + 3);
                *reinterpret_cast<f32x4*>(oslab + e) = v;
            }
        }
        __syncthreads();   // keep the block's write front tight per slab
    }
}

extern "C" void kernel_launch(void* const* d_in, const int* in_sizes, int n_in,
                              void* d_out, int out_size, void* d_ws, size_t ws_size,
                              hipStream_t stream)
{
    const float* x     = (const float*)d_in[0];
    const float* alpha = (const float*)d_in[1];
    float* out = (float*)d_out;

    fofe_kernel<<<GRID, 512, 0, stream>>>(x, alpha, out);
}